// Round 4
// baseline (2013.939 us; speedup 1.0000x reference)
//
#include <hip/hip_runtime.h>
#include <math.h>

// Persistent-kernel ResonatorABC scan — tagged dataflow + arrival-driven select.
// Grid: 128 WGs x 1024 threads. WG w owns features [8w,8w+8) for ALL 128 rows
// (B-reductions WG-local) and runs the exact radix select for row b==wg.
// Cross-WG words (score, tauB, tauC) are 64-bit {tag=t+1 | value} agent-scope
// atomics. Round-0 histogram is arrival-driven (ballot + leader-counted
// atomics) so producer skew is absorbed, not serialized. Taus are polled by
// 256 designated threads into LDS and broadcast via one syncthreads.

#define T_STEPS 128
#define B_DIM   128
#define F_DIM   1024
#define NWG     128
#define NTH     1024
#define BF      (B_DIM * F_DIM)

typedef unsigned long long ull;

__device__ __forceinline__ ull ld64(const ull* p) {
  return __hip_atomic_load(p, __ATOMIC_RELAXED, __HIP_MEMORY_SCOPE_AGENT);
}
__device__ __forceinline__ void st64(ull* p, ull v) {
  __hip_atomic_store(p, v, __ATOMIC_RELAXED, __HIP_MEMORY_SCOPE_AGENT);
}

extern "C" __global__ void __launch_bounds__(NTH)
ResonatorABC_82094004896068_kernel(
    const float* __restrict__ in_re, const float* __restrict__ in_im,
    const float* __restrict__ r_re_p, const float* __restrict__ r_im_p,
    const float* __restrict__ alpha_map, const float* __restrict__ lambda_map,
    float* __restrict__ out, ull* __restrict__ ws)
{
  const int tid  = threadIdx.x;
  const int wg   = blockIdx.x;
  const int b    = tid >> 3;        // batch row of this thread
  const int fl   = tid & 7;         // feature-local index
  const int f    = (wg << 3) + fl;  // global feature
  const int wid  = tid >> 6;        // wave id (0..15)
  const int lane = tid & 63;
  const int idx  = b * F_DIM + f;

  ull* score64 = ws;                // [B][F] {tag|score_bits}
  ull* tauB64  = ws + BF;           // [128]
  ull* tauC64  = ws + BF + 128;     // [128]

  __shared__ __align__(16) float pamp[16][8][4];    // wave partials: amp, amp^2, unit_re, unit_im
  __shared__ __align__(16) float pev[16][8][2];     // wave partials: evB, evC
  __shared__ __align__(16) unsigned h0[256];        // round-0 shared histogram
  __shared__ __align__(16) unsigned h123[3][4][260];// rounds 1-3, up to 4 runs each
  __shared__ unsigned dpref[4];                     // resolved prefixes (ranks 255,256,767,768)
  __shared__ unsigned drank[4];                     // residual ranks
  __shared__ float tauLds[256];                     // gathered taus: [0..127]=B, [128..255]=C

  float af = fminf(fmaxf(0.97f + 0.05f * tanhf(alpha_map[f]), 0.90f), 0.995f);
  float lf = fminf(fmaxf(0.95f + 0.05f * tanhf(lambda_map[f]), 0.90f), 0.995f);
  float rr = r_re_p[f];
  float ri = r_im_p[f];
  const float c002 = cosf(0.02f);
  const float s002 = sinf(0.02f);

  float X_re = 0.f, X_im = 0.f, sA = 0.f, sB = 0.f, sC = 0.f;
  float mu = 0.f, var = 0.01f, theta = 0.1f, ema_re = 0.f, ema_im = 0.f;

  float ur = in_re[idx];
  float ui = in_im[idx];

  for (int t = 0; t < T_STEPS; ++t) {
    const ull want = (ull)(t + 1);

    // ---- loop-top: zero all histogram buffers + init rank state (covered by pamp sync) ----
    {
      unsigned* hz = &h123[0][0][0];
      #pragma unroll
      for (int i = 0; i < 4; ++i) {
        int j = tid + i * NTH;
        if (j < 3 * 4 * 260) hz[j] = 0u;
      }
      if (tid < 256) h0[tid] = 0u;
      if (tid < 4) {
        dpref[tid] = 0u;
        drank[tid] = (tid == 0) ? 255u : (tid == 1) ? 256u : (tid == 2) ? 767u : 768u;
      }
    }

    // ---------------- Phase 1: elementwise + B-reduced stats + score ----------------
    float Xm_re = af * X_re + ur;
    float Xm_im = af * X_im + ui;
    float amp2 = Xm_re * Xm_re + Xm_im * Xm_im;
    float amp  = sqrtf(amp2);
    float invamp = (amp > 0.f) ? (1.0f / amp) : 0.f;
    float un_re = (amp > 0.f) ? (Xm_re * invamp) : 1.0f;  // angle(0)=0 -> unit=1
    float un_im = Xm_im * invamp;
    float proj = Xm_re * rr + Xm_im * ri;                 // Re(X_mid * conj(r))
    sA = lf * sA + proj;
    out[t * BF + idx] = sA;

    float r0 = amp, r1 = amp2, r2 = un_re, r3 = un_im;
    for (int m = 8; m < 64; m <<= 1) {
      r0 += __shfl_xor(r0, m);
      r1 += __shfl_xor(r1, m);
      r2 += __shfl_xor(r2, m);
      r3 += __shfl_xor(r3, m);
    }
    if (lane < 8) { pamp[wid][lane][0]=r0; pamp[wid][lane][1]=r1; pamp[wid][lane][2]=r2; pamp[wid][lane][3]=r3; }
    __syncthreads();
    float S0=0.f, S1=0.f, S2=0.f, S3=0.f;
    #pragma unroll
    for (int w = 0; w < 16; ++w) {
      float4 p = *(const float4*)&pamp[w][fl][0];
      S0 += p.x; S1 += p.y; S2 += p.z; S3 += p.w;
    }
    float m1 = S0 * 0.0078125f;      // mean(amp)
    float m2 = S1 * 0.0078125f;      // mean(amp^2)
    mu = 0.9f * mu + 0.1f * m1;
    float vm = m2 - 2.f * mu * m1 + mu * mu;
    vm = fmaxf(vm, 0.f);
    var = 0.9f * var + 0.1f * vm;
    ema_re = 0.9f * ema_re + 0.1f * (S2 * 0.0078125f);
    ema_im = 0.9f * ema_im + 0.1f * (S3 * 0.0078125f);
    float plv = sqrtf(ema_re * ema_re + ema_im * ema_im);
    float zs = (amp - mu) / (sqrtf(var) + 1e-3f);
    float score = amp + 0.5f * fabsf(zs) + 0.5f * (1.0f - plv);
    st64(&score64[idx], (want << 32) | (ull)__float_as_uint(score));

    // prefetch next-step inputs; loads in flight during the select
    float ur_n = 0.f, ui_n = 0.f;
    if (t + 1 < T_STEPS) {
      ur_n = in_re[(t + 1) * BF + idx];
      ui_n = in_im[(t + 1) * BF + idx];
    }

    // ---------------- Phase 2: exact radix select (ranks 255,256,767,768) ----------------
    unsigned uval;
    {
      // Round 0 histogram, arrival-driven: process lanes as their words arrive.
      const ull* sp_ = &score64[wg * F_DIM + tid];
      ull v; bool have = false; unsigned uv = 0u;
      unsigned long long done = 0ull;
      while (done != ~0ull) {
        if (!have) {
          v = ld64(sp_);
          if ((v >> 32) == want) { have = true; uv = (unsigned)v; }
        }
        unsigned long long newly = __ballot(have) & ~done;
        while (newly) {
          int leader = __builtin_ctzll(newly);
          unsigned d = __shfl(uv >> 24, leader);
          unsigned long long same = __ballot(have && ((uv >> 24) == d)) & newly;
          if (lane == leader) atomicAdd(&h0[d], (unsigned)__popcll(same));
          newly &= ~same;
          done |= same;
        }
        if (done != ~0ull) __builtin_amdgcn_s_sleep(1);
      }
      uval = uv;   // score >= 0: uint order == float order
    }
    __syncthreads();   // h0 complete

    for (int rnd = 0; rnd < 4; ++rnd) {
      const int shift = 24 - 8 * rnd;
      if (rnd > 0) {
        // add phase: only elements matching a surviving run prefix
        const unsigned msk = 0xFFFFFFFFu << (32 - 8 * rnd);
        unsigned p0 = dpref[0], p1 = dpref[1], p2 = dpref[2], p3 = dpref[3];
        unsigned runpref[4];
        int nruns = 1;
        runpref[0] = p0;
        if (p1 != p0) runpref[nruns++] = p1;
        if (p2 != runpref[nruns - 1]) runpref[nruns++] = p2;
        if (p3 != runpref[nruns - 1]) runpref[nruns++] = p3;
        unsigned key = uval & msk;
        int run = -1;
        if (key == runpref[0]) run = 0;
        else if (nruns > 1 && key == runpref[1]) run = 1;
        else if (nruns > 2 && key == runpref[2]) run = 2;
        else if (nruns > 3 && key == runpref[3]) run = 3;
        if (run >= 0) atomicAdd(&h123[rnd - 1][run][(uval >> shift) & 255u], 1u);
        __syncthreads();   // histogram complete
      }
      if (wid == 0) {
        unsigned p0 = dpref[0], p1 = dpref[1], p2 = dpref[2], p3 = dpref[3];
        unsigned runpref[4];
        int nruns = 1;
        runpref[0] = p0;
        if (p1 != p0) runpref[nruns++] = p1;
        if (p2 != runpref[nruns - 1]) runpref[nruns++] = p2;
        if (p3 != runpref[nruns - 1]) runpref[nruns++] = p3;
        const unsigned* Hbase = (rnd == 0) ? h0 : &h123[rnd - 1][0][0];
        for (int rix = 0; rix < nruns; ++rix) {
          uint4 h = *(const uint4*)&Hbase[rix * 260 + 4 * lane];
          unsigned scnt = h.x + h.y + h.z + h.w;
          unsigned incl = scnt;
          #pragma unroll
          for (int d = 1; d < 64; d <<= 1) {
            unsigned vv = __shfl_up(incl, d);
            if (lane >= d) incl += vv;
          }
          unsigned excl = incl - scnt;
          #pragma unroll
          for (int sidx = 0; sidx < 4; ++sidx) {
            unsigned sp = (sidx == 0) ? p0 : (sidx == 1) ? p1 : (sidx == 2) ? p2 : p3;
            if (sp != runpref[rix]) continue;
            unsigned k = drank[sidx];
            unsigned long long m64 = __ballot(incl > k);
            int l0 = __builtin_ctzll(m64);
            unsigned base = __shfl(excl, l0);
            unsigned h0v = __shfl(h.x, l0);
            unsigned h1v = __shfl(h.y, l0);
            unsigned h2v = __shfl(h.z, l0);
            unsigned h3v = __shfl(h.w, l0);
            int bsel; unsigned nk;
            unsigned bacc = base;
            if (k < bacc + h0v) { bsel = 0; nk = k - bacc; }
            else { bacc += h0v;
              if (k < bacc + h1v) { bsel = 1; nk = k - bacc; }
              else { bacc += h1v;
                if (k < bacc + h2v) { bsel = 2; nk = k - bacc; }
                else { bacc += h2v; bsel = 3; nk = k - bacc; } } }
            if (lane == 0) {
              dpref[sidx] = sp | ((unsigned)(4 * l0 + bsel) << shift);
              drank[sidx] = nk;
            }
          }
        }
        if (rnd == 3 && lane == 0) {
          float s255 = __uint_as_float(dpref[0]);
          float s256 = __uint_as_float(dpref[1]);
          float s767 = __uint_as_float(dpref[2]);
          float s768 = __uint_as_float(dpref[3]);
          float tb = 0.75f * s767 + 0.25f * s768;           // quantile(score, .75)
          float tc = -(0.75f * s256 + 0.25f * s255);        // quantile(-score, .75)
          st64(&tauB64[wg], (want << 32) | (ull)__float_as_uint(tb));
          st64(&tauC64[wg], (want << 32) | (ull)__float_as_uint(tc));
        }
      }
      __syncthreads();
    }

    // ---------------- tau gather: 256 pollers -> LDS broadcast ----------------
    if (tid < 256) {
      const ull* src = (tid < 128) ? &tauB64[tid] : &tauC64[tid - 128];
      ull v = ld64(src);
      while ((v >> 32) != want) { __builtin_amdgcn_s_sleep(1); v = ld64(src); }
      tauLds[tid] = __uint_as_float((unsigned)v);
    }
    __syncthreads();
    float tb = tauLds[b];
    float tc = tauLds[128 + b];

    // ---------------- Phase 3: gates, s-updates, events, theta/corr, reentry ----------------
    float gB = 1.0f / (1.0f + expf(-5.0f * (score - tb)));
    float gC = 1.0f / (1.0f + expf(-5.0f * (-score - tc)));
    sB = lf * sB + proj * gB;
    sC = lf * sC + proj * gC;
    float e0 = (sB >= theta) ? 1.0f : 0.0f;   // old theta
    float e1 = (sC >= theta) ? 1.0f : 0.0f;
    for (int m = 8; m < 64; m <<= 1) {
      e0 += __shfl_xor(e0, m);
      e1 += __shfl_xor(e1, m);
    }
    if (lane < 8) { pev[wid][lane][0] = e0; pev[wid][lane][1] = e1; }
    __syncthreads();
    float cB = 0.f, cC = 0.f;
    #pragma unroll
    for (int w = 0; w < 16; ++w) {
      float2 p = *(const float2*)&pev[w][fl][0];
      cB += p.x; cC += p.y;
    }
    float th1 = theta + 0.01f * (cB * 0.0078125f) - 0.01f * (cC * 0.0078125f);
    theta = fminf(fmaxf(th1 - 0.01f * (th1 - 0.1f), 0.01f), 10.0f);
    float fac_re = 1.0f, fac_im = 0.0f;
    if (cB > 0.f) { fac_re = c002 + 0.1f * gB; fac_im = s002; }
    X_re = Xm_re * fac_re - Xm_im * fac_im;
    X_im = Xm_re * fac_im + Xm_im * fac_re;

    ur = ur_n; ui = ui_n;
  }
}

extern "C" void kernel_launch(void* const* d_in, const int* in_sizes, int n_in,
                              void* d_out, int out_size, void* d_ws, size_t ws_size,
                              hipStream_t stream) {
  const float* in_re = (const float*)d_in[0];
  const float* in_im = (const float*)d_in[1];
  const float* r_re  = (const float*)d_in[2];
  const float* r_im  = (const float*)d_in[3];
  const float* amap  = (const float*)d_in[4];
  const float* lmap  = (const float*)d_in[5];
  float* out = (float*)d_out;
  ull* ws = (ull*)d_ws;
  // zero all tag words so no stale/garbage tag can match (re-recorded in graph)
  hipMemsetAsync(d_ws, 0, (size_t)(BF + 256) * 8, stream);
  hipLaunchKernelGGL(ResonatorABC_82094004896068_kernel,
                     dim3(NWG), dim3(NTH), 0, stream,
                     in_re, in_im, r_re, r_im, amap, lmap, out, ws);
}

// Round 5
// 1254.787 us; speedup vs baseline: 1.6050x; 1.6050x over previous
//
#include <hip/hip_runtime.h>
#include <math.h>

// Persistent-kernel ResonatorABC scan — tagged dataflow + linear-bin exact select.
// Grid: 128 WGs x 1024 threads. WG w owns features [8w,8w+8) for ALL 128 rows
// (B-reductions WG-local) and runs the exact rank select for row b==wg.
// Cross-WG words (score, tauB, tauC) are 64-bit {tag=t+1 | value} agent-scope
// atomics with simple per-thread polling (fastest measured arrival scheme).
// Select: min/max -> 1024 linear bins -> histogram -> parallel prefix scan ->
// tiny-list exact rank resolve (4 waves in parallel). Exact fallback refine
// loop for degenerate (>256-duplicate) bins. Bit-identical order statistics.

#define T_STEPS 128
#define B_DIM   128
#define F_DIM   1024
#define NWG     128
#define NTH     1024
#define BF      (B_DIM * F_DIM)

typedef unsigned long long ull;

__device__ __forceinline__ ull ld64(const ull* p) {
  return __hip_atomic_load(p, __ATOMIC_RELAXED, __HIP_MEMORY_SCOPE_AGENT);
}
__device__ __forceinline__ void st64(ull* p, ull v) {
  __hip_atomic_store(p, v, __ATOMIC_RELAXED, __HIP_MEMORY_SCOPE_AGENT);
}

extern "C" __global__ void __launch_bounds__(NTH)
ResonatorABC_82094004896068_kernel(
    const float* __restrict__ in_re, const float* __restrict__ in_im,
    const float* __restrict__ r_re_p, const float* __restrict__ r_im_p,
    const float* __restrict__ alpha_map, const float* __restrict__ lambda_map,
    float* __restrict__ out, ull* __restrict__ ws)
{
  const int tid  = threadIdx.x;
  const int wg   = blockIdx.x;
  const int b    = tid >> 3;        // batch row of this thread
  const int fl   = tid & 7;         // feature-local index
  const int f    = (wg << 3) + fl;  // global feature
  const int wid  = tid >> 6;        // wave id (0..15)
  const int lane = tid & 63;
  const int idx  = b * F_DIM + f;

  ull* score64 = ws;                // [B][F] {tag|score_bits}
  ull* tauB64  = ws + BF;           // [128]
  ull* tauC64  = ws + BF + 128;     // [128]

  __shared__ __align__(16) float pamp[16][8][4];   // wave partials: amp, amp2, unit_re, unit_im
  __shared__ __align__(16) float pfin[8][4];       // final per-feature sums
  __shared__ __align__(16) float pev[16][8][2];    // wave partials: evB, evC
  __shared__ __align__(16) float evfin[8][2];      // final per-feature event sums
  __shared__ unsigned h[1024];                     // histogram (1024 bins)
  __shared__ unsigned wsum[16];                    // per-wave scan totals
  __shared__ unsigned mmw[16][2];                  // per-wave min/max
  __shared__ unsigned mmu[2];                      // WG min/max
  __shared__ unsigned tbin[4], tbase[4], tcnt[4];  // located rank bins
  __shared__ unsigned lcnt[4];                     // list counters
  __shared__ unsigned lists[4][256];               // extracted bin values
  __shared__ unsigned resv[4], resf[4];            // resolved rank values/flags
  __shared__ unsigned rmm[2];                      // refine min/max
  __shared__ unsigned t2[3];                       // refine located bin/base/cnt
  __shared__ float tauLds[256];                    // gathered taus

  float af = fminf(fmaxf(0.97f + 0.05f * tanhf(alpha_map[f]), 0.90f), 0.995f);
  float lf = fminf(fmaxf(0.95f + 0.05f * tanhf(lambda_map[f]), 0.90f), 0.995f);
  float rr = r_re_p[f];
  float ri = r_im_p[f];
  const float c002 = cosf(0.02f);
  const float s002 = sinf(0.02f);

  float X_re = 0.f, X_im = 0.f, sA = 0.f, sB = 0.f, sC = 0.f;
  float mu = 0.f, var = 0.01f, theta = 0.1f, ema_re = 0.f, ema_im = 0.f;

  float ur = in_re[idx];
  float ui = in_im[idx];

  const unsigned KR0 = 255u, KR1 = 256u, KR2 = 767u, KR3 = 768u;

  for (int t = 0; t < T_STEPS; ++t) {
    const ull want = (ull)(t + 1);

    h[tid] = 0u;   // zeroed every step; separated from use by phase-1 syncs

    // ---------------- Phase 1: elementwise + B-reduced stats + score ----------------
    float Xm_re = af * X_re + ur;
    float Xm_im = af * X_im + ui;
    float amp2 = Xm_re * Xm_re + Xm_im * Xm_im;
    float amp  = sqrtf(amp2);
    float invamp = (amp > 0.f) ? (1.0f / amp) : 0.f;
    float un_re = (amp > 0.f) ? (Xm_re * invamp) : 1.0f;  // angle(0)=0 -> unit=1
    float un_im = Xm_im * invamp;
    float proj = Xm_re * rr + Xm_im * ri;                 // Re(X_mid * conj(r))
    sA = lf * sA + proj;
    out[t * BF + idx] = sA;

    float r0 = amp, r1 = amp2, r2 = un_re, r3 = un_im;
    #pragma unroll
    for (int m = 8; m < 64; m <<= 1) {
      r0 += __shfl_xor(r0, m);
      r1 += __shfl_xor(r1, m);
      r2 += __shfl_xor(r2, m);
      r3 += __shfl_xor(r3, m);
    }
    if (lane < 8) { *(float4*)&pamp[wid][lane][0] = make_float4(r0, r1, r2, r3); }
    __syncthreads();
    if (tid < 32) {   // summers: one per (feature, quantity)
      int sfl = tid >> 2, q = tid & 3;
      float s = 0.f;
      #pragma unroll
      for (int w = 0; w < 16; ++w) s += pamp[w][sfl][q];
      pfin[sfl][q] = s;
    }
    __syncthreads();
    float4 SS = *(const float4*)&pfin[fl][0];
    float m1 = SS.x * 0.0078125f;      // mean(amp)
    float m2 = SS.y * 0.0078125f;      // mean(amp^2)
    mu = 0.9f * mu + 0.1f * m1;
    float vm = m2 - 2.f * mu * m1 + mu * mu;
    vm = fmaxf(vm, 0.f);
    var = 0.9f * var + 0.1f * vm;
    ema_re = 0.9f * ema_re + 0.1f * (SS.z * 0.0078125f);
    ema_im = 0.9f * ema_im + 0.1f * (SS.w * 0.0078125f);
    float plv = sqrtf(ema_re * ema_re + ema_im * ema_im);
    float zs = (amp - mu) / (sqrtf(var) + 1e-3f);
    float score = amp + 0.5f * fabsf(zs) + 0.5f * (1.0f - plv);
    st64(&score64[idx], (want << 32) | (ull)__float_as_uint(score));

    // prefetch next-step inputs; latency hidden behind select
    float ur_n = 0.f, ui_n = 0.f;
    if (t + 1 < T_STEPS) {
      ur_n = in_re[(t + 1) * BF + idx];
      ui_n = in_im[(t + 1) * BF + idx];
    }

    // ---------------- Phase 2: exact select of ranks {255,256,767,768} for row wg ----
    const ull* spoll = &score64[wg * F_DIM + tid];
    ull v = ld64(spoll);
    while ((v >> 32) != want) { __builtin_amdgcn_s_sleep(1); v = ld64(spoll); }
    unsigned uval = (unsigned)v;        // score >= 0: uint order == float order

    // WG min/max
    unsigned umin = uval, umax = uval;
    #pragma unroll
    for (int m = 1; m < 64; m <<= 1) {
      umin = min(umin, (unsigned)__shfl_xor((int)umin, m));
      umax = max(umax, (unsigned)__shfl_xor((int)umax, m));
    }
    if (lane == 0) { mmw[wid][0] = umin; mmw[wid][1] = umax; }
    __syncthreads();
    if (tid < 16) {
      unsigned a = mmw[tid][0], c = mmw[tid][1];
      #pragma unroll
      for (int m = 1; m < 16; m <<= 1) {
        a = min(a, (unsigned)__shfl_xor((int)a, m));
        c = max(c, (unsigned)__shfl_xor((int)c, m));
      }
      if (tid == 0) { mmu[0] = a; mmu[1] = c; }
    }
    __syncthreads();
    unsigned lo = mmu[0], hi = mmu[1];

    if (lo != hi) {
      ull rng = (ull)hi - (ull)lo + 1ull;
      ull inv = (1ull << 40) / rng;      // floor; bin map monotone, bounded <=1023
      unsigned bin = (unsigned)((((ull)(uval - lo)) * inv) >> 30);
      atomicAdd(&h[bin], 1u);
      __syncthreads();
      unsigned cnt = h[tid];             // thread owns bin `tid`
      unsigned incl = cnt;
      #pragma unroll
      for (int d = 1; d < 64; d <<= 1) {
        unsigned vv = __shfl_up(incl, d);
        if (lane >= d) incl += vv;
      }
      if (lane == 63) wsum[wid] = incl;
      __syncthreads();
      if (tid < 16) {
        unsigned wv = wsum[tid], wincl = wv;
        #pragma unroll
        for (int d = 1; d < 16; d <<= 1) {
          unsigned x = __shfl_up(wincl, d);
          if (tid >= d) wincl += x;
        }
        wsum[tid] = wincl - wv;          // exclusive wave offset
      }
      if (tid < 4) { lcnt[tid] = 0u; resf[tid] = 0u; }
      __syncthreads();
      unsigned base = wsum[wid] + (incl - cnt);
      if (cnt > 0u) {
        if (base <= KR0 && KR0 < base + cnt) { tbin[0] = tid; tbase[0] = base; tcnt[0] = cnt; }
        if (base <= KR1 && KR1 < base + cnt) { tbin[1] = tid; tbase[1] = base; tcnt[1] = cnt; }
        if (base <= KR2 && KR2 < base + cnt) { tbin[2] = tid; tbase[2] = base; tcnt[2] = cnt; }
        if (base <= KR3 && KR3 < base + cnt) { tbin[3] = tid; tbase[3] = base; tcnt[3] = cnt; }
      }
      __syncthreads();
      // build lists (dedup: add to first list of each distinct bin; bins sorted)
      unsigned b0 = tbin[0], b1 = tbin[1], b2 = tbin[2], b3 = tbin[3];
      if (bin == b0) { unsigned s = atomicAdd(&lcnt[0], 1u); if (s < 256u) lists[0][s] = uval; }
      else if (bin == b1 && b1 != b0) { unsigned s = atomicAdd(&lcnt[1], 1u); if (s < 256u) lists[1][s] = uval; }
      else if (bin == b2 && b2 != b1) { unsigned s = atomicAdd(&lcnt[2], 1u); if (s < 256u) lists[2][s] = uval; }
      else if (bin == b3 && b3 != b2) { unsigned s = atomicAdd(&lcnt[3], 1u); if (s < 256u) lists[3][s] = uval; }
      __syncthreads();
      if (wid < 4) {   // wave j resolves rank j (parallel)
        const int j = wid;
        const unsigned KRj = (j == 0) ? KR0 : (j == 1) ? KR1 : (j == 2) ? KR2 : KR3;
        int src = j;
        while (src > 0 && tbin[src - 1] == tbin[j]) --src;   // uniform per wave
        unsigned c = tcnt[j];
        if (c <= 256u) {
          unsigned kk = KRj - tbase[j];
          for (int bi = 0; bi < (int)c; bi += 64) {
            int i = bi + lane;
            if (i < (int)c) {
              unsigned e = lists[src][i];
              unsigned r = 0;
              for (int q = 0; q < (int)c; ++q) {
                unsigned x = lists[src][q];
                r += (x < e || (x == e && q < i)) ? 1u : 0u;
              }
              if (r == kk) { resv[j] = e; resf[j] = 1u; }
            }
          }
        }
      }
      __syncthreads();
      // rare exact refine for any unresolved rank (degenerate duplicate-heavy bins)
      for (int j = 0; j < 4; ++j) {
        if (resf[j]) continue;   // uniform (LDS, post-sync)
        const unsigned KRj = (j == 0) ? KR0 : (j == 1) ? KR1 : (j == 2) ? KR2 : KR3;
        bool inj = (bin == tbin[j]);
        unsigned krem = KRj - tbase[j];
        for (int iter = 0; iter < 40; ++iter) {
          if (tid == 0) { rmm[0] = 0xFFFFFFFFu; rmm[1] = 0u; }
          __syncthreads();
          if (inj) { atomicMin(&rmm[0], uval); atomicMax(&rmm[1], uval); }
          __syncthreads();
          unsigned wlo = rmm[0], whi = rmm[1];
          if (wlo == whi) { if (tid == 0) { resv[j] = wlo; resf[j] = 1u; } __syncthreads(); break; }
          h[tid] = 0u;
          __syncthreads();
          ull rng2 = (ull)whi - (ull)wlo + 1ull;
          ull inv2 = (1ull << 40) / rng2;
          unsigned nb = inj ? (unsigned)((((ull)(uval - wlo)) * inv2) >> 30) : 0u;
          if (inj) atomicAdd(&h[nb], 1u);
          __syncthreads();
          unsigned cnt2 = h[tid];
          unsigned incl2 = cnt2;
          #pragma unroll
          for (int d = 1; d < 64; d <<= 1) {
            unsigned vv = __shfl_up(incl2, d);
            if (lane >= d) incl2 += vv;
          }
          if (lane == 63) wsum[wid] = incl2;
          __syncthreads();
          if (tid < 16) {
            unsigned wv = wsum[tid], wincl = wv;
            #pragma unroll
            for (int d = 1; d < 16; d <<= 1) {
              unsigned x = __shfl_up(wincl, d);
              if (tid >= d) wincl += x;
            }
            wsum[tid] = wincl - wv;
          }
          if (tid == 0) lcnt[0] = 0u;
          __syncthreads();
          unsigned base2 = wsum[wid] + (incl2 - cnt2);
          if (cnt2 > 0u && base2 <= krem && krem < base2 + cnt2) {
            t2[0] = tid; t2[1] = base2; t2[2] = cnt2;
          }
          __syncthreads();
          unsigned nbin = t2[0], nbase = t2[1], ncnt = t2[2];
          bool newin = inj && (nb == nbin);
          if (ncnt <= 256u) {
            if (newin) { unsigned s = atomicAdd(&lcnt[0], 1u); if (s < 256u) lists[0][s] = uval; }
            __syncthreads();
            if (wid == 0) {
              unsigned kk2 = krem - nbase;
              for (int bi = 0; bi < (int)ncnt; bi += 64) {
                int i = bi + lane;
                if (i < (int)ncnt) {
                  unsigned e = lists[0][i];
                  unsigned r = 0;
                  for (int q = 0; q < (int)ncnt; ++q) {
                    unsigned x = lists[0][q];
                    r += (x < e || (x == e && q < i)) ? 1u : 0u;
                  }
                  if (r == kk2) { resv[j] = e; resf[j] = 1u; }
                }
              }
            }
            __syncthreads();
            break;
          }
          inj = newin; krem = krem - nbase;
        }
      }
    } else {
      if (tid < 4) { resv[tid] = lo; resf[tid] = 1u; }
      __syncthreads();
    }
    if (tid == 0) {
      float s255 = __uint_as_float(resv[0]);
      float s256 = __uint_as_float(resv[1]);
      float s767 = __uint_as_float(resv[2]);
      float s768 = __uint_as_float(resv[3]);
      float tb = 0.75f * s767 + 0.25f * s768;           // quantile(score, .75)
      float tc = -(0.75f * s256 + 0.25f * s255);        // quantile(-score, .75)
      st64(&tauB64[wg], (want << 32) | (ull)__float_as_uint(tb));
      st64(&tauC64[wg], (want << 32) | (ull)__float_as_uint(tc));
    }

    // ---------------- tau gather: 256 pollers -> LDS broadcast ----------------
    if (tid < 256) {
      const ull* src = (tid < 128) ? &tauB64[tid] : &tauC64[tid - 128];
      ull v2 = ld64(src);
      while ((v2 >> 32) != want) { __builtin_amdgcn_s_sleep(1); v2 = ld64(src); }
      tauLds[tid] = __uint_as_float((unsigned)v2);
    }
    __syncthreads();
    float tb = tauLds[b];
    float tc = tauLds[128 + b];

    // ---------------- Phase 3: gates, s-updates, events, theta/corr, reentry ----------
    float gB = 1.0f / (1.0f + expf(-5.0f * (score - tb)));
    float gC = 1.0f / (1.0f + expf(-5.0f * (-score - tc)));
    sB = lf * sB + proj * gB;
    sC = lf * sC + proj * gC;
    float e0 = (sB >= theta) ? 1.0f : 0.0f;   // old theta
    float e1 = (sC >= theta) ? 1.0f : 0.0f;
    #pragma unroll
    for (int m = 8; m < 64; m <<= 1) {
      e0 += __shfl_xor(e0, m);
      e1 += __shfl_xor(e1, m);
    }
    if (lane < 8) { pev[wid][lane][0] = e0; pev[wid][lane][1] = e1; }
    __syncthreads();
    if (tid < 16) {   // summers: one per (feature, quantity)
      int sfl = tid >> 1, q = tid & 1;
      float s = 0.f;
      #pragma unroll
      for (int w = 0; w < 16; ++w) s += pev[w][sfl][q];
      evfin[sfl][q] = s;
    }
    __syncthreads();
    float cB = evfin[fl][0];
    float cC = evfin[fl][1];
    float th1 = theta + 0.01f * (cB * 0.0078125f) - 0.01f * (cC * 0.0078125f);
    theta = fminf(fmaxf(th1 - 0.01f * (th1 - 0.1f), 0.01f), 10.0f);
    float fac_re = 1.0f, fac_im = 0.0f;
    if (cB > 0.f) { fac_re = c002 + 0.1f * gB; fac_im = s002; }
    X_re = Xm_re * fac_re - Xm_im * fac_im;
    X_im = Xm_re * fac_im + Xm_im * fac_re;

    ur = ur_n; ui = ui_n;
  }
}

extern "C" void kernel_launch(void* const* d_in, const int* in_sizes, int n_in,
                              void* d_out, int out_size, void* d_ws, size_t ws_size,
                              hipStream_t stream) {
  const float* in_re = (const float*)d_in[0];
  const float* in_im = (const float*)d_in[1];
  const float* r_re  = (const float*)d_in[2];
  const float* r_im  = (const float*)d_in[3];
  const float* amap  = (const float*)d_in[4];
  const float* lmap  = (const float*)d_in[5];
  float* out = (float*)d_out;
  ull* ws = (ull*)d_ws;
  // zero all tag words so no stale/garbage tag can match
  hipMemsetAsync(d_ws, 0, (size_t)(BF + 256) * 8, stream);
  hipLaunchKernelGGL(ResonatorABC_82094004896068_kernel,
                     dim3(NWG), dim3(NTH), 0, stream,
                     in_re, in_im, r_re, r_im, amap, lmap, out, ws);
}

// Round 7
// 1207.606 us; speedup vs baseline: 1.6677x; 1.0391x over previous
//
#include <hip/hip_runtime.h>
#include <math.h>

// Persistent-kernel ResonatorABC scan — tagged dataflow + linear-bin exact select.
// Grid: 128 WGs x 256 threads (4 waves). WG w owns features [8w,8w+8) for ALL
// 128 rows; each thread owns 4 (b,f) elements: b = rg+32k, k=0..3, f = 8w+fl.
// B-reductions are WG-local (wave shfl + 4 partials). WG w also runs the exact
// rank select {255,256,767,768} for row b==w on the score matrix in scratch.
// Cross-WG words (score, tauB, tauC) are 64-bit {tag=t+1 | value} agent-scope
// atomics with per-thread polling. 4 waves -> cheap barriers.
// ROUND-6 BUG FIXED: phase 3 must gate with the thread's OWN score[k], not the
// polled select-row value uval[k].

#define T_STEPS 128
#define B_DIM   128
#define F_DIM   1024
#define NWG     128
#define NTH     256
#define BF      (B_DIM * F_DIM)

typedef unsigned long long ull;

__device__ __forceinline__ ull ld64(const ull* p) {
  return __hip_atomic_load(p, __ATOMIC_RELAXED, __HIP_MEMORY_SCOPE_AGENT);
}
__device__ __forceinline__ void st64(ull* p, ull v) {
  __hip_atomic_store(p, v, __ATOMIC_RELAXED, __HIP_MEMORY_SCOPE_AGENT);
}

extern "C" __global__ void __launch_bounds__(NTH)
ResonatorABC_82094004896068_kernel(
    const float* __restrict__ in_re, const float* __restrict__ in_im,
    const float* __restrict__ r_re_p, const float* __restrict__ r_im_p,
    const float* __restrict__ alpha_map, const float* __restrict__ lambda_map,
    float* __restrict__ out, ull* __restrict__ ws)
{
  const int tid  = threadIdx.x;
  const int wg   = blockIdx.x;
  const int fl   = tid & 7;         // feature-local index
  const int rg   = tid >> 3;        // row-group base (0..31); rows rg+32k
  const int f    = (wg << 3) + fl;  // global feature
  const int wid  = tid >> 6;        // wave id (0..3)
  const int lane = tid & 63;

  ull* score64 = ws;                // [B][F] {tag|score_bits}
  ull* tauB64  = ws + BF;           // [128]
  ull* tauC64  = ws + BF + 128;     // [128]

  __shared__ __align__(16) float pamp[4][8][4];   // wave partials: amp, amp2, unit_re, unit_im
  __shared__ __align__(16) float pfin[8][4];      // final per-feature sums
  __shared__ __align__(16) float pev[4][8][2];    // wave partials: evB, evC
  __shared__ __align__(16) float evfin[8][2];     // final per-feature event sums
  __shared__ __align__(16) unsigned h[1024];      // histogram (1024 bins)
  __shared__ unsigned wsum[4];                    // per-wave scan totals
  __shared__ unsigned mmw[4][2];                  // per-wave min/max
  __shared__ unsigned tbin[4], tbase[4], tcnt[4]; // located rank bins
  __shared__ unsigned lcnt[4];                    // list counters
  __shared__ unsigned lists[4][256];              // extracted bin values
  __shared__ unsigned resv[4], resf[4];           // resolved rank values/flags
  __shared__ unsigned rmm[2];                     // refine min/max
  __shared__ unsigned t2[3];                      // refine located bin/base/cnt
  __shared__ float tauLds[256];                   // gathered taus

  const float af = fminf(fmaxf(0.97f + 0.05f * tanhf(alpha_map[f]), 0.90f), 0.995f);
  const float lf = fminf(fmaxf(0.95f + 0.05f * tanhf(lambda_map[f]), 0.90f), 0.995f);
  const float rr = r_re_p[f];
  const float ri = r_im_p[f];
  const float c002 = cosf(0.02f);
  const float s002 = sinf(0.02f);

  // per-element carried state (4 rows of feature f)
  float X_re[4] = {0.f,0.f,0.f,0.f}, X_im[4] = {0.f,0.f,0.f,0.f};
  float sA[4] = {0.f,0.f,0.f,0.f}, sB[4] = {0.f,0.f,0.f,0.f}, sC[4] = {0.f,0.f,0.f,0.f};
  // per-feature carried state (single copy)
  float mu = 0.f, var = 0.01f, theta = 0.1f, ema_re = 0.f, ema_im = 0.f;

  int idx[4];
  float ur[4], ui[4];
  #pragma unroll
  for (int k = 0; k < 4; ++k) {
    idx[k] = (rg + 32 * k) * F_DIM + f;
    ur[k] = in_re[idx[k]];
    ui[k] = in_im[idx[k]];
  }

  const unsigned KR[4] = {255u, 256u, 767u, 768u};

  for (int t = 0; t < T_STEPS; ++t) {
    const ull want = (ull)(t + 1);

    *(uint4*)&h[4 * tid] = make_uint4(0u, 0u, 0u, 0u);   // zero hist (covered by phase-1 syncs)

    // ---------------- Phase 1: elementwise + B-reduced stats + score ----------------
    float Xm_re[4], Xm_im[4], proj[4], amp[4], score[4];
    float a0 = 0.f, a1 = 0.f, a2 = 0.f, a3 = 0.f;
    #pragma unroll
    for (int k = 0; k < 4; ++k) {
      Xm_re[k] = af * X_re[k] + ur[k];
      Xm_im[k] = af * X_im[k] + ui[k];
      float amp2 = Xm_re[k] * Xm_re[k] + Xm_im[k] * Xm_im[k];
      amp[k] = sqrtf(amp2);
      float invamp = (amp[k] > 0.f) ? (1.0f / amp[k]) : 0.f;
      float un_re = (amp[k] > 0.f) ? (Xm_re[k] * invamp) : 1.0f;  // angle(0)=0 -> unit=1
      float un_im = Xm_im[k] * invamp;
      proj[k] = Xm_re[k] * rr + Xm_im[k] * ri;                    // Re(X_mid*conj(r))
      sA[k] = lf * sA[k] + proj[k];
      out[t * BF + idx[k]] = sA[k];
      a0 += amp[k]; a1 += amp2; a2 += un_re; a3 += un_im;
    }
    #pragma unroll
    for (int m = 8; m < 64; m <<= 1) {   // reduce over row-groups within wave
      a0 += __shfl_xor(a0, m);
      a1 += __shfl_xor(a1, m);
      a2 += __shfl_xor(a2, m);
      a3 += __shfl_xor(a3, m);
    }
    if (lane < 8) { *(float4*)&pamp[wid][lane][0] = make_float4(a0, a1, a2, a3); }
    __syncthreads();
    if (tid < 32) {   // summers: one per (feature, quantity)
      int sfl = tid >> 2, q = tid & 3;
      pfin[sfl][q] = pamp[0][sfl][q] + pamp[1][sfl][q] + pamp[2][sfl][q] + pamp[3][sfl][q];
    }
    __syncthreads();
    float4 SS = *(const float4*)&pfin[fl][0];
    float m1 = SS.x * 0.0078125f;      // mean(amp)
    float m2 = SS.y * 0.0078125f;      // mean(amp^2)
    mu = 0.9f * mu + 0.1f * m1;
    float vm = m2 - 2.f * mu * m1 + mu * mu;
    vm = fmaxf(vm, 0.f);
    var = 0.9f * var + 0.1f * vm;
    ema_re = 0.9f * ema_re + 0.1f * (SS.z * 0.0078125f);
    ema_im = 0.9f * ema_im + 0.1f * (SS.w * 0.0078125f);
    float plv = sqrtf(ema_re * ema_re + ema_im * ema_im);
    float sden = sqrtf(var) + 1e-3f;
    #pragma unroll
    for (int k = 0; k < 4; ++k) {
      float zs = (amp[k] - mu) / sden;
      score[k] = amp[k] + 0.5f * fabsf(zs) + 0.5f * (1.0f - plv);
      st64(&score64[idx[k]], (want << 32) | (ull)__float_as_uint(score[k]));
    }

    // prefetch next-step inputs; latency hidden behind select
    float ur_n[4] = {0.f,0.f,0.f,0.f}, ui_n[4] = {0.f,0.f,0.f,0.f};
    if (t + 1 < T_STEPS) {
      #pragma unroll
      for (int k = 0; k < 4; ++k) {
        ur_n[k] = in_re[(t + 1) * BF + idx[k]];
        ui_n[k] = in_im[(t + 1) * BF + idx[k]];
      }
    }

    // ---------------- Phase 2: exact select of ranks {255,256,767,768} for row wg ----
    unsigned uval[4], bin[4];
    {
      const ull* sp0 = &score64[wg * F_DIM + tid];
      #pragma unroll
      for (int k = 0; k < 4; ++k) {
        ull v = ld64(sp0 + 256 * k);
        while ((v >> 32) != want) { __builtin_amdgcn_s_sleep(1); v = ld64(sp0 + 256 * k); }
        uval[k] = (unsigned)v;       // score >= 0: uint order == float order
      }
    }
    unsigned umin = min(min(uval[0], uval[1]), min(uval[2], uval[3]));
    unsigned umax = max(max(uval[0], uval[1]), max(uval[2], uval[3]));
    #pragma unroll
    for (int m = 1; m < 64; m <<= 1) {
      umin = min(umin, (unsigned)__shfl_xor((int)umin, m));
      umax = max(umax, (unsigned)__shfl_xor((int)umax, m));
    }
    if (lane == 0) { mmw[wid][0] = umin; mmw[wid][1] = umax; }
    __syncthreads();
    unsigned lo = min(min(mmw[0][0], mmw[1][0]), min(mmw[2][0], mmw[3][0]));
    unsigned hi = max(max(mmw[0][1], mmw[1][1]), max(mmw[2][1], mmw[3][1]));

    if (lo != hi) {
      ull rng = (ull)hi - (ull)lo + 1ull;
      ull inv = (1ull << 40) / rng;      // floor; bin map monotone, bounded <=1023
      #pragma unroll
      for (int k = 0; k < 4; ++k) {
        bin[k] = (unsigned)((((ull)(uval[k] - lo)) * inv) >> 30);
        atomicAdd(&h[bin[k]], 1u);
      }
      if (tid < 4) { lcnt[tid] = 0u; resf[tid] = 0u; }
      __syncthreads();
      // scan: thread owns 4 consecutive bins
      uint4 hc = *(const uint4*)&h[4 * tid];
      unsigned s4 = hc.x + hc.y + hc.z + hc.w;
      unsigned incl = s4;
      #pragma unroll
      for (int d = 1; d < 64; d <<= 1) {
        unsigned vv = __shfl_up(incl, d);
        if (lane >= d) incl += vv;
      }
      if (lane == 63) wsum[wid] = incl;
      __syncthreads();
      unsigned woff = 0u;
      for (int w = 0; w < 4; ++w) if (w < wid) woff += wsum[w];
      unsigned gexcl = woff + incl - s4;       // exclusive base of my 4-bin group
      unsigned cv[4] = {hc.x, hc.y, hc.z, hc.w};
      unsigned bb[4];
      bb[0] = gexcl; bb[1] = bb[0] + cv[0]; bb[2] = bb[1] + cv[1]; bb[3] = bb[2] + cv[2];
      #pragma unroll
      for (int i = 0; i < 4; ++i) {
        if (cv[i] > 0u) {
          #pragma unroll
          for (int r = 0; r < 4; ++r) {
            if (bb[i] <= KR[r] && KR[r] < bb[i] + cv[i]) {
              tbin[r] = 4 * tid + i; tbase[r] = bb[i]; tcnt[r] = cv[i];
            }
          }
        }
      }
      __syncthreads();
      // build lists (dedup: add to first list of each distinct bin; tbin non-decreasing)
      unsigned b0 = tbin[0], b1 = tbin[1], b2 = tbin[2], b3 = tbin[3];
      #pragma unroll
      for (int k = 0; k < 4; ++k) {
        unsigned bk = bin[k], uv = uval[k];
        if (bk == b0) { unsigned s = atomicAdd(&lcnt[0], 1u); if (s < 256u) lists[0][s] = uv; }
        else if (bk == b1 && b1 != b0) { unsigned s = atomicAdd(&lcnt[1], 1u); if (s < 256u) lists[1][s] = uv; }
        else if (bk == b2 && b2 != b1) { unsigned s = atomicAdd(&lcnt[2], 1u); if (s < 256u) lists[2][s] = uv; }
        else if (bk == b3 && b3 != b2) { unsigned s = atomicAdd(&lcnt[3], 1u); if (s < 256u) lists[3][s] = uv; }
      }
      __syncthreads();
      {   // wave j resolves rank j (all 4 waves busy)
        const int j = wid;
        int src = j;
        while (src > 0 && tbin[src - 1] == tbin[j]) --src;   // uniform per wave
        unsigned c = tcnt[j];
        if (c <= 256u) {
          unsigned kk = KR[j] - tbase[j];
          for (int bi = 0; bi < (int)c; bi += 64) {
            int i = bi + lane;
            if (i < (int)c) {
              unsigned e = lists[src][i];
              unsigned r = 0;
              for (int q = 0; q < (int)c; ++q) {
                unsigned x = lists[src][q];
                r += (x < e || (x == e && q < i)) ? 1u : 0u;
              }
              if (r == kk) { resv[j] = e; resf[j] = 1u; }
            }
          }
        }
      }
      __syncthreads();
      // rare exact refine for any unresolved rank (degenerate duplicate-heavy bins)
      for (int j = 0; j < 4; ++j) {
        if (resf[j]) continue;   // uniform (LDS, post-sync)
        bool inj[4];
        #pragma unroll
        for (int k = 0; k < 4; ++k) inj[k] = (bin[k] == tbin[j]);
        unsigned krem = KR[j] - tbase[j];
        for (int iter = 0; iter < 40; ++iter) {
          if (tid == 0) { rmm[0] = 0xFFFFFFFFu; rmm[1] = 0u; }
          __syncthreads();
          #pragma unroll
          for (int k = 0; k < 4; ++k)
            if (inj[k]) { atomicMin(&rmm[0], uval[k]); atomicMax(&rmm[1], uval[k]); }
          __syncthreads();
          unsigned wlo = rmm[0], whi = rmm[1];
          if (wlo == whi) { if (tid == 0) { resv[j] = wlo; resf[j] = 1u; } __syncthreads(); break; }
          *(uint4*)&h[4 * tid] = make_uint4(0u, 0u, 0u, 0u);
          __syncthreads();
          ull rng2 = (ull)whi - (ull)wlo + 1ull;
          ull inv2 = (1ull << 40) / rng2;
          unsigned nb[4];
          #pragma unroll
          for (int k = 0; k < 4; ++k) {
            nb[k] = inj[k] ? (unsigned)((((ull)(uval[k] - wlo)) * inv2) >> 30) : 0u;
            if (inj[k]) atomicAdd(&h[nb[k]], 1u);
          }
          __syncthreads();
          uint4 hc2 = *(const uint4*)&h[4 * tid];
          unsigned s42 = hc2.x + hc2.y + hc2.z + hc2.w;
          unsigned incl2 = s42;
          #pragma unroll
          for (int d = 1; d < 64; d <<= 1) {
            unsigned vv = __shfl_up(incl2, d);
            if (lane >= d) incl2 += vv;
          }
          if (lane == 63) wsum[wid] = incl2;
          if (tid == 0) lcnt[0] = 0u;
          __syncthreads();
          unsigned woff2 = 0u;
          for (int w = 0; w < 4; ++w) if (w < wid) woff2 += wsum[w];
          unsigned gexcl2 = woff2 + incl2 - s42;
          unsigned cv2[4] = {hc2.x, hc2.y, hc2.z, hc2.w};
          unsigned bb2[4];
          bb2[0] = gexcl2; bb2[1] = bb2[0] + cv2[0]; bb2[2] = bb2[1] + cv2[1]; bb2[3] = bb2[2] + cv2[2];
          #pragma unroll
          for (int i = 0; i < 4; ++i) {
            if (cv2[i] > 0u && bb2[i] <= krem && krem < bb2[i] + cv2[i]) {
              t2[0] = 4 * tid + i; t2[1] = bb2[i]; t2[2] = cv2[i];
            }
          }
          __syncthreads();
          unsigned nbin = t2[0], nbase = t2[1], ncnt = t2[2];
          bool newin[4];
          #pragma unroll
          for (int k = 0; k < 4; ++k) newin[k] = inj[k] && (nb[k] == nbin);
          if (ncnt <= 256u) {
            #pragma unroll
            for (int k = 0; k < 4; ++k)
              if (newin[k]) { unsigned s = atomicAdd(&lcnt[0], 1u); if (s < 256u) lists[0][s] = uval[k]; }
            __syncthreads();
            if (wid == 0) {
              unsigned kk2 = krem - nbase;
              for (int bi = 0; bi < (int)ncnt; bi += 64) {
                int i = bi + lane;
                if (i < (int)ncnt) {
                  unsigned e = lists[0][i];
                  unsigned r = 0;
                  for (int q = 0; q < (int)ncnt; ++q) {
                    unsigned x = lists[0][q];
                    r += (x < e || (x == e && q < i)) ? 1u : 0u;
                  }
                  if (r == kk2) { resv[j] = e; resf[j] = 1u; }
                }
              }
            }
            __syncthreads();
            break;
          }
          #pragma unroll
          for (int k = 0; k < 4; ++k) inj[k] = newin[k];
          krem -= nbase;
        }
      }
    } else {
      if (tid < 4) { resv[tid] = lo; resf[tid] = 1u; }
      __syncthreads();
    }
    if (tid == 0) {
      float s255 = __uint_as_float(resv[0]);
      float s256 = __uint_as_float(resv[1]);
      float s767 = __uint_as_float(resv[2]);
      float s768 = __uint_as_float(resv[3]);
      float tb = 0.75f * s767 + 0.25f * s768;           // quantile(score, .75)
      float tc = -(0.75f * s256 + 0.25f * s255);        // quantile(-score, .75)
      st64(&tauB64[wg], (want << 32) | (ull)__float_as_uint(tb));
      st64(&tauC64[wg], (want << 32) | (ull)__float_as_uint(tc));
    }

    // ---------------- tau gather: 256 pollers -> LDS broadcast ----------------
    {
      const ull* src = (tid < 128) ? &tauB64[tid] : &tauC64[tid - 128];
      ull v2 = ld64(src);
      while ((v2 >> 32) != want) { __builtin_amdgcn_s_sleep(1); v2 = ld64(src); }
      tauLds[tid] = __uint_as_float((unsigned)v2);
    }
    __syncthreads();

    // ---------------- Phase 3: gates, s-updates, events, theta/corr, reentry ----------
    float gB[4];
    float e0 = 0.f, e1 = 0.f;
    #pragma unroll
    for (int k = 0; k < 4; ++k) {
      float tb = tauLds[rg + 32 * k];
      float tc = tauLds[128 + rg + 32 * k];
      float sc = score[k];                   // OWN score (round-6 bug: was uval[k])
      gB[k] = 1.0f / (1.0f + expf(-5.0f * (sc - tb)));
      float gC = 1.0f / (1.0f + expf(-5.0f * (-sc - tc)));
      sB[k] = lf * sB[k] + proj[k] * gB[k];
      sC[k] = lf * sC[k] + proj[k] * gC;
      e0 += (sB[k] >= theta) ? 1.0f : 0.0f;   // old theta
      e1 += (sC[k] >= theta) ? 1.0f : 0.0f;
    }
    #pragma unroll
    for (int m = 8; m < 64; m <<= 1) {
      e0 += __shfl_xor(e0, m);
      e1 += __shfl_xor(e1, m);
    }
    if (lane < 8) { pev[wid][lane][0] = e0; pev[wid][lane][1] = e1; }
    __syncthreads();
    if (tid < 16) {   // summers
      int sfl = tid >> 1, q = tid & 1;
      evfin[sfl][q] = pev[0][sfl][q] + pev[1][sfl][q] + pev[2][sfl][q] + pev[3][sfl][q];
    }
    __syncthreads();
    float cB = evfin[fl][0];
    float cC = evfin[fl][1];
    float th1 = theta + 0.01f * (cB * 0.0078125f) - 0.01f * (cC * 0.0078125f);
    theta = fminf(fmaxf(th1 - 0.01f * (th1 - 0.1f), 0.01f), 10.0f);
    bool corr = (cB > 0.f);
    #pragma unroll
    for (int k = 0; k < 4; ++k) {
      float fac_re = corr ? (c002 + 0.1f * gB[k]) : 1.0f;
      float fac_im = corr ? s002 : 0.0f;
      X_re[k] = Xm_re[k] * fac_re - Xm_im[k] * fac_im;
      X_im[k] = Xm_re[k] * fac_im + Xm_im[k] * fac_re;
      ur[k] = ur_n[k]; ui[k] = ui_n[k];
    }
  }
}

extern "C" void kernel_launch(void* const* d_in, const int* in_sizes, int n_in,
                              void* d_out, int out_size, void* d_ws, size_t ws_size,
                              hipStream_t stream) {
  const float* in_re = (const float*)d_in[0];
  const float* in_im = (const float*)d_in[1];
  const float* r_re  = (const float*)d_in[2];
  const float* r_im  = (const float*)d_in[3];
  const float* amap  = (const float*)d_in[4];
  const float* lmap  = (const float*)d_in[5];
  float* out = (float*)d_out;
  ull* ws = (ull*)d_ws;
  // zero all tag words so no stale/garbage tag can match
  hipMemsetAsync(d_ws, 0, (size_t)(BF + 256) * 8, stream);
  hipLaunchKernelGGL(ResonatorABC_82094004896068_kernel,
                     dim3(NWG), dim3(NTH), 0, stream,
                     in_re, in_im, r_re, r_im, amap, lmap, out, ws);
}

// Round 8
// 1202.596 us; speedup vs baseline: 1.6747x; 1.0042x over previous
//
#include <hip/hip_runtime.h>
#include <math.h>

// Persistent-kernel ResonatorABC scan — tagged dataflow + linear-bin exact select
// + per-consumer TAU MAILBOXES (writer-side fan-out).
// Grid: 128 WGs x 256 threads (4 waves). WG w owns features [8w,8w+8) for ALL
// 128 rows; each thread owns 4 (b,f) elements: b = rg+32k, f = 8w+fl.
// Round-7 analysis: all-WGs-poll-same-tau-lines contention at the coherence
// point was the suspected dominant cost. Now selector WG fans its taus out to
// 128 private mailboxes (1 reader/line); score poll made concurrent (4 loads
// in flight, re-poll only stale).

#define T_STEPS 128
#define B_DIM   128
#define F_DIM   1024
#define NWG     128
#define NTH     256
#define BF      (B_DIM * F_DIM)

typedef unsigned long long ull;

__device__ __forceinline__ ull ld64(const ull* p) {
  return __hip_atomic_load(p, __ATOMIC_RELAXED, __HIP_MEMORY_SCOPE_AGENT);
}
__device__ __forceinline__ void st64(ull* p, ull v) {
  __hip_atomic_store(p, v, __ATOMIC_RELAXED, __HIP_MEMORY_SCOPE_AGENT);
}

extern "C" __global__ void __launch_bounds__(NTH)
ResonatorABC_82094004896068_kernel(
    const float* __restrict__ in_re, const float* __restrict__ in_im,
    const float* __restrict__ r_re_p, const float* __restrict__ r_im_p,
    const float* __restrict__ alpha_map, const float* __restrict__ lambda_map,
    float* __restrict__ out, ull* __restrict__ ws)
{
  const int tid  = threadIdx.x;
  const int wg   = blockIdx.x;
  const int fl   = tid & 7;         // feature-local index
  const int rg   = tid >> 3;        // row-group base (0..31); rows rg+32k
  const int f    = (wg << 3) + fl;  // global feature
  const int wid  = tid >> 6;        // wave id (0..3)
  const int lane = tid & 63;

  ull* score64 = ws;                // [B][F] {tag|score_bits}
  ull* taubox  = ws + BF;           // [128 consumers][256 slots] {tag|tau_bits}
                                    // slot b: tauB row b; slot 128+b: tauC row b

  __shared__ __align__(16) float pamp[4][8][4];   // wave partials: amp, amp2, unit_re, unit_im
  __shared__ __align__(16) float pfin[8][4];      // final per-feature sums
  __shared__ __align__(16) float pev[4][8][2];    // wave partials: evB, evC
  __shared__ __align__(16) float evfin[8][2];     // final per-feature event sums
  __shared__ __align__(16) unsigned h[1024];      // histogram (1024 bins)
  __shared__ unsigned wsum[4];                    // per-wave scan totals
  __shared__ unsigned mmw[4][2];                  // per-wave min/max
  __shared__ unsigned tbin[4], tbase[4], tcnt[4]; // located rank bins
  __shared__ unsigned lcnt[4];                    // list counters
  __shared__ unsigned lists[4][256];              // extracted bin values
  __shared__ unsigned resv[4], resf[4];           // resolved rank values/flags
  __shared__ unsigned rmm[2];                     // refine min/max
  __shared__ unsigned t2[3];                      // refine located bin/base/cnt
  __shared__ float tauLds[256];                   // gathered taus

  const float af = fminf(fmaxf(0.97f + 0.05f * tanhf(alpha_map[f]), 0.90f), 0.995f);
  const float lf = fminf(fmaxf(0.95f + 0.05f * tanhf(lambda_map[f]), 0.90f), 0.995f);
  const float rr = r_re_p[f];
  const float ri = r_im_p[f];
  const float c002 = cosf(0.02f);
  const float s002 = sinf(0.02f);

  // per-element carried state (4 rows of feature f)
  float X_re[4] = {0.f,0.f,0.f,0.f}, X_im[4] = {0.f,0.f,0.f,0.f};
  float sA[4] = {0.f,0.f,0.f,0.f}, sB[4] = {0.f,0.f,0.f,0.f}, sC[4] = {0.f,0.f,0.f,0.f};
  // per-feature carried state (single copy)
  float mu = 0.f, var = 0.01f, theta = 0.1f, ema_re = 0.f, ema_im = 0.f;

  int idx[4];
  float ur[4], ui[4];
  #pragma unroll
  for (int k = 0; k < 4; ++k) {
    idx[k] = (rg + 32 * k) * F_DIM + f;
    ur[k] = in_re[idx[k]];
    ui[k] = in_im[idx[k]];
  }

  const unsigned KR[4] = {255u, 256u, 767u, 768u};

  for (int t = 0; t < T_STEPS; ++t) {
    const ull want = (ull)(t + 1);

    *(uint4*)&h[4 * tid] = make_uint4(0u, 0u, 0u, 0u);   // zero hist (covered by phase-1 syncs)

    // ---------------- Phase 1: elementwise + B-reduced stats + score ----------------
    float Xm_re[4], Xm_im[4], proj[4], amp[4], score[4];
    float a0 = 0.f, a1 = 0.f, a2 = 0.f, a3 = 0.f;
    #pragma unroll
    for (int k = 0; k < 4; ++k) {
      Xm_re[k] = af * X_re[k] + ur[k];
      Xm_im[k] = af * X_im[k] + ui[k];
      float amp2 = Xm_re[k] * Xm_re[k] + Xm_im[k] * Xm_im[k];
      amp[k] = sqrtf(amp2);
      float invamp = (amp[k] > 0.f) ? (1.0f / amp[k]) : 0.f;
      float un_re = (amp[k] > 0.f) ? (Xm_re[k] * invamp) : 1.0f;  // angle(0)=0 -> unit=1
      float un_im = Xm_im[k] * invamp;
      proj[k] = Xm_re[k] * rr + Xm_im[k] * ri;                    // Re(X_mid*conj(r))
      sA[k] = lf * sA[k] + proj[k];
      out[t * BF + idx[k]] = sA[k];
      a0 += amp[k]; a1 += amp2; a2 += un_re; a3 += un_im;
    }
    #pragma unroll
    for (int m = 8; m < 64; m <<= 1) {   // reduce over row-groups within wave
      a0 += __shfl_xor(a0, m);
      a1 += __shfl_xor(a1, m);
      a2 += __shfl_xor(a2, m);
      a3 += __shfl_xor(a3, m);
    }
    if (lane < 8) { *(float4*)&pamp[wid][lane][0] = make_float4(a0, a1, a2, a3); }
    __syncthreads();
    if (tid < 32) {   // summers: one per (feature, quantity)
      int sfl = tid >> 2, q = tid & 3;
      pfin[sfl][q] = pamp[0][sfl][q] + pamp[1][sfl][q] + pamp[2][sfl][q] + pamp[3][sfl][q];
    }
    __syncthreads();
    float4 SS = *(const float4*)&pfin[fl][0];
    float m1 = SS.x * 0.0078125f;      // mean(amp)
    float m2 = SS.y * 0.0078125f;      // mean(amp^2)
    mu = 0.9f * mu + 0.1f * m1;
    float vm = m2 - 2.f * mu * m1 + mu * mu;
    vm = fmaxf(vm, 0.f);
    var = 0.9f * var + 0.1f * vm;
    ema_re = 0.9f * ema_re + 0.1f * (SS.z * 0.0078125f);
    ema_im = 0.9f * ema_im + 0.1f * (SS.w * 0.0078125f);
    float plv = sqrtf(ema_re * ema_re + ema_im * ema_im);
    float sden = sqrtf(var) + 1e-3f;
    #pragma unroll
    for (int k = 0; k < 4; ++k) {
      float zs = (amp[k] - mu) / sden;
      score[k] = amp[k] + 0.5f * fabsf(zs) + 0.5f * (1.0f - plv);
      st64(&score64[idx[k]], (want << 32) | (ull)__float_as_uint(score[k]));
    }

    // prefetch next-step inputs; latency hidden behind select
    float ur_n[4] = {0.f,0.f,0.f,0.f}, ui_n[4] = {0.f,0.f,0.f,0.f};
    if (t + 1 < T_STEPS) {
      #pragma unroll
      for (int k = 0; k < 4; ++k) {
        ur_n[k] = in_re[(t + 1) * BF + idx[k]];
        ui_n[k] = in_im[(t + 1) * BF + idx[k]];
      }
    }

    // ---------------- Phase 2: exact select of ranks {255,256,767,768} for row wg ----
    unsigned uval[4], bin[4];
    {
      // concurrent 4-way poll: all 4 loads in flight, re-poll only stale words
      const ull* sp0 = &score64[wg * F_DIM + tid];
      ull v[4]; bool ok[4] = {false, false, false, false};
      int remaining = 4;
      while (remaining) {
        #pragma unroll
        for (int k = 0; k < 4; ++k) if (!ok[k]) v[k] = ld64(sp0 + 256 * k);
        #pragma unroll
        for (int k = 0; k < 4; ++k) {
          if (!ok[k] && (v[k] >> 32) == want) { ok[k] = true; uval[k] = (unsigned)v[k]; --remaining; }
        }
        if (remaining) __builtin_amdgcn_s_sleep(1);
      }
    }
    unsigned umin = min(min(uval[0], uval[1]), min(uval[2], uval[3]));
    unsigned umax = max(max(uval[0], uval[1]), max(uval[2], uval[3]));
    #pragma unroll
    for (int m = 1; m < 64; m <<= 1) {
      umin = min(umin, (unsigned)__shfl_xor((int)umin, m));
      umax = max(umax, (unsigned)__shfl_xor((int)umax, m));
    }
    if (lane == 0) { mmw[wid][0] = umin; mmw[wid][1] = umax; }
    __syncthreads();
    unsigned lo = min(min(mmw[0][0], mmw[1][0]), min(mmw[2][0], mmw[3][0]));
    unsigned hi = max(max(mmw[0][1], mmw[1][1]), max(mmw[2][1], mmw[3][1]));

    if (lo != hi) {
      ull rng = (ull)hi - (ull)lo + 1ull;
      ull inv = (1ull << 40) / rng;      // floor; bin map monotone, bounded <=1023
      #pragma unroll
      for (int k = 0; k < 4; ++k) {
        bin[k] = (unsigned)((((ull)(uval[k] - lo)) * inv) >> 30);
        atomicAdd(&h[bin[k]], 1u);
      }
      if (tid < 4) { lcnt[tid] = 0u; resf[tid] = 0u; }
      __syncthreads();
      // scan: thread owns 4 consecutive bins
      uint4 hc = *(const uint4*)&h[4 * tid];
      unsigned s4 = hc.x + hc.y + hc.z + hc.w;
      unsigned incl = s4;
      #pragma unroll
      for (int d = 1; d < 64; d <<= 1) {
        unsigned vv = __shfl_up(incl, d);
        if (lane >= d) incl += vv;
      }
      if (lane == 63) wsum[wid] = incl;
      __syncthreads();
      unsigned woff = 0u;
      for (int w = 0; w < 4; ++w) if (w < wid) woff += wsum[w];
      unsigned gexcl = woff + incl - s4;       // exclusive base of my 4-bin group
      unsigned cv[4] = {hc.x, hc.y, hc.z, hc.w};
      unsigned bb[4];
      bb[0] = gexcl; bb[1] = bb[0] + cv[0]; bb[2] = bb[1] + cv[1]; bb[3] = bb[2] + cv[2];
      #pragma unroll
      for (int i = 0; i < 4; ++i) {
        if (cv[i] > 0u) {
          #pragma unroll
          for (int r = 0; r < 4; ++r) {
            if (bb[i] <= KR[r] && KR[r] < bb[i] + cv[i]) {
              tbin[r] = 4 * tid + i; tbase[r] = bb[i]; tcnt[r] = cv[i];
            }
          }
        }
      }
      __syncthreads();
      // build lists (dedup: add to first list of each distinct bin; tbin non-decreasing)
      unsigned b0 = tbin[0], b1 = tbin[1], b2 = tbin[2], b3 = tbin[3];
      #pragma unroll
      for (int k = 0; k < 4; ++k) {
        unsigned bk = bin[k], uv = uval[k];
        if (bk == b0) { unsigned s = atomicAdd(&lcnt[0], 1u); if (s < 256u) lists[0][s] = uv; }
        else if (bk == b1 && b1 != b0) { unsigned s = atomicAdd(&lcnt[1], 1u); if (s < 256u) lists[1][s] = uv; }
        else if (bk == b2 && b2 != b1) { unsigned s = atomicAdd(&lcnt[2], 1u); if (s < 256u) lists[2][s] = uv; }
        else if (bk == b3 && b3 != b2) { unsigned s = atomicAdd(&lcnt[3], 1u); if (s < 256u) lists[3][s] = uv; }
      }
      __syncthreads();
      {   // wave j resolves rank j (all 4 waves busy)
        const int j = wid;
        int src = j;
        while (src > 0 && tbin[src - 1] == tbin[j]) --src;   // uniform per wave
        unsigned c = tcnt[j];
        if (c <= 256u) {
          unsigned kk = KR[j] - tbase[j];
          for (int bi = 0; bi < (int)c; bi += 64) {
            int i = bi + lane;
            if (i < (int)c) {
              unsigned e = lists[src][i];
              unsigned r = 0;
              for (int q = 0; q < (int)c; ++q) {
                unsigned x = lists[src][q];
                r += (x < e || (x == e && q < i)) ? 1u : 0u;
              }
              if (r == kk) { resv[j] = e; resf[j] = 1u; }
            }
          }
        }
      }
      __syncthreads();
      // rare exact refine for any unresolved rank (degenerate duplicate-heavy bins)
      for (int j = 0; j < 4; ++j) {
        if (resf[j]) continue;   // uniform (LDS, post-sync)
        bool inj[4];
        #pragma unroll
        for (int k = 0; k < 4; ++k) inj[k] = (bin[k] == tbin[j]);
        unsigned krem = KR[j] - tbase[j];
        for (int iter = 0; iter < 40; ++iter) {
          if (tid == 0) { rmm[0] = 0xFFFFFFFFu; rmm[1] = 0u; }
          __syncthreads();
          #pragma unroll
          for (int k = 0; k < 4; ++k)
            if (inj[k]) { atomicMin(&rmm[0], uval[k]); atomicMax(&rmm[1], uval[k]); }
          __syncthreads();
          unsigned wlo = rmm[0], whi = rmm[1];
          if (wlo == whi) { if (tid == 0) { resv[j] = wlo; resf[j] = 1u; } __syncthreads(); break; }
          *(uint4*)&h[4 * tid] = make_uint4(0u, 0u, 0u, 0u);
          __syncthreads();
          ull rng2 = (ull)whi - (ull)wlo + 1ull;
          ull inv2 = (1ull << 40) / rng2;
          unsigned nb[4];
          #pragma unroll
          for (int k = 0; k < 4; ++k) {
            nb[k] = inj[k] ? (unsigned)((((ull)(uval[k] - wlo)) * inv2) >> 30) : 0u;
            if (inj[k]) atomicAdd(&h[nb[k]], 1u);
          }
          __syncthreads();
          uint4 hc2 = *(const uint4*)&h[4 * tid];
          unsigned s42 = hc2.x + hc2.y + hc2.z + hc2.w;
          unsigned incl2 = s42;
          #pragma unroll
          for (int d = 1; d < 64; d <<= 1) {
            unsigned vv = __shfl_up(incl2, d);
            if (lane >= d) incl2 += vv;
          }
          if (lane == 63) wsum[wid] = incl2;
          if (tid == 0) lcnt[0] = 0u;
          __syncthreads();
          unsigned woff2 = 0u;
          for (int w = 0; w < 4; ++w) if (w < wid) woff2 += wsum[w];
          unsigned gexcl2 = woff2 + incl2 - s42;
          unsigned cv2[4] = {hc2.x, hc2.y, hc2.z, hc2.w};
          unsigned bb2[4];
          bb2[0] = gexcl2; bb2[1] = bb2[0] + cv2[0]; bb2[2] = bb2[1] + cv2[1]; bb2[3] = bb2[2] + cv2[2];
          #pragma unroll
          for (int i = 0; i < 4; ++i) {
            if (cv2[i] > 0u && bb2[i] <= krem && krem < bb2[i] + cv2[i]) {
              t2[0] = 4 * tid + i; t2[1] = bb2[i]; t2[2] = cv2[i];
            }
          }
          __syncthreads();
          unsigned nbin = t2[0], nbase = t2[1], ncnt = t2[2];
          bool newin[4];
          #pragma unroll
          for (int k = 0; k < 4; ++k) newin[k] = inj[k] && (nb[k] == nbin);
          if (ncnt <= 256u) {
            #pragma unroll
            for (int k = 0; k < 4; ++k)
              if (newin[k]) { unsigned s = atomicAdd(&lcnt[0], 1u); if (s < 256u) lists[0][s] = uval[k]; }
            __syncthreads();
            if (wid == 0) {
              unsigned kk2 = krem - nbase;
              for (int bi = 0; bi < (int)ncnt; bi += 64) {
                int i = bi + lane;
                if (i < (int)ncnt) {
                  unsigned e = lists[0][i];
                  unsigned r = 0;
                  for (int q = 0; q < (int)ncnt; ++q) {
                    unsigned x = lists[0][q];
                    r += (x < e || (x == e && q < i)) ? 1u : 0u;
                  }
                  if (r == kk2) { resv[j] = e; resf[j] = 1u; }
                }
              }
            }
            __syncthreads();
            break;
          }
          #pragma unroll
          for (int k = 0; k < 4; ++k) inj[k] = newin[k];
          krem -= nbase;
        }
      }
    } else {
      if (tid < 4) { resv[tid] = lo; resf[tid] = 1u; }
      __syncthreads();
    }

    // ---------------- tau publish: fan out to all 128 consumer mailboxes ----------
    {
      // resv[] visible to all threads (post-sync). All threads compute both taus.
      float s255 = __uint_as_float(resv[0]);
      float s256 = __uint_as_float(resv[1]);
      float s767 = __uint_as_float(resv[2]);
      float s768 = __uint_as_float(resv[3]);
      float tb = 0.75f * s767 + 0.25f * s768;           // quantile(score, .75)
      float tc = -(0.75f * s256 + 0.25f * s255);        // quantile(-score, .75)
      int c = tid & 127;                                // consumer WG
      ull w = (tid < 128)
            ? ((want << 32) | (ull)__float_as_uint(tb))
            : ((want << 32) | (ull)__float_as_uint(tc));
      int slot = (tid < 128) ? wg : (128 + wg);
      st64(&taubox[(ull)c * 256 + slot], w);
    }

    // ---------------- tau gather: poll OWN mailbox (sole reader) -> LDS ----------
    {
      const ull* src = &taubox[(ull)wg * 256 + tid];
      ull v2 = ld64(src);
      while ((v2 >> 32) != want) { __builtin_amdgcn_s_sleep(1); v2 = ld64(src); }
      tauLds[tid] = __uint_as_float((unsigned)v2);
    }
    __syncthreads();

    // ---------------- Phase 3: gates, s-updates, events, theta/corr, reentry ----------
    float gB[4];
    float e0 = 0.f, e1 = 0.f;
    #pragma unroll
    for (int k = 0; k < 4; ++k) {
      float tb = tauLds[rg + 32 * k];
      float tc = tauLds[128 + rg + 32 * k];
      float sc = score[k];                   // own score
      gB[k] = 1.0f / (1.0f + expf(-5.0f * (sc - tb)));
      float gC = 1.0f / (1.0f + expf(-5.0f * (-sc - tc)));
      sB[k] = lf * sB[k] + proj[k] * gB[k];
      sC[k] = lf * sC[k] + proj[k] * gC;
      e0 += (sB[k] >= theta) ? 1.0f : 0.0f;   // old theta
      e1 += (sC[k] >= theta) ? 1.0f : 0.0f;
    }
    #pragma unroll
    for (int m = 8; m < 64; m <<= 1) {
      e0 += __shfl_xor(e0, m);
      e1 += __shfl_xor(e1, m);
    }
    if (lane < 8) { pev[wid][lane][0] = e0; pev[wid][lane][1] = e1; }
    __syncthreads();
    if (tid < 16) {   // summers
      int sfl = tid >> 1, q = tid & 1;
      evfin[sfl][q] = pev[0][sfl][q] + pev[1][sfl][q] + pev[2][sfl][q] + pev[3][sfl][q];
    }
    __syncthreads();
    float cB = evfin[fl][0];
    float cC = evfin[fl][1];
    float th1 = theta + 0.01f * (cB * 0.0078125f) - 0.01f * (cC * 0.0078125f);
    theta = fminf(fmaxf(th1 - 0.01f * (th1 - 0.1f), 0.01f), 10.0f);
    bool corr = (cB > 0.f);
    #pragma unroll
    for (int k = 0; k < 4; ++k) {
      float fac_re = corr ? (c002 + 0.1f * gB[k]) : 1.0f;
      float fac_im = corr ? s002 : 0.0f;
      X_re[k] = Xm_re[k] * fac_re - Xm_im[k] * fac_im;
      X_im[k] = Xm_re[k] * fac_im + Xm_im[k] * fac_re;
      ur[k] = ur_n[k]; ui[k] = ui_n[k];
    }
  }
}

extern "C" void kernel_launch(void* const* d_in, const int* in_sizes, int n_in,
                              void* d_out, int out_size, void* d_ws, size_t ws_size,
                              hipStream_t stream) {
  const float* in_re = (const float*)d_in[0];
  const float* in_im = (const float*)d_in[1];
  const float* r_re  = (const float*)d_in[2];
  const float* r_im  = (const float*)d_in[3];
  const float* amap  = (const float*)d_in[4];
  const float* lmap  = (const float*)d_in[5];
  float* out = (float*)d_out;
  ull* ws = (ull*)d_ws;
  // zero all tag words (score + mailboxes) so no stale tag can match
  hipMemsetAsync(d_ws, 0, (size_t)(BF + 128 * 256) * 8, stream);
  hipLaunchKernelGGL(ResonatorABC_82094004896068_kernel,
                     dim3(NWG), dim3(NTH), 0, stream,
                     in_re, in_im, r_re, r_im, amap, lmap, out, ws);
}